// Round 5
// baseline (311.526 us; speedup 1.0000x reference)
//
#include <hip/hip_runtime.h>

#define BS 256
#define NQ 512
#define NC 128
#define NP 256
#define NG 128
#define TQ 32
#define PTS (NC + 1)   // padded predAct tile stride: bank = (qo + aid) % 32, conflict-free gather
#define BIGC 1.0e6f
#define EPSC 1e-6f

// Single fused kernel. Block = (batch b, q-half). Row-LSEs computed in-block
// into LDS (att slab read ONCE from HBM); then 8 q-tiles of the verified
// phase A->C3 pipeline, att column tiles re-read from L3. No workspace.
__global__ __launch_bounds__(512, 4) void cost_fused(
    const float* __restrict__ predAct,   // [BS,NQ,NC]
    const float* __restrict__ att,       // [BS,NP,NQ]
    const int*   __restrict__ actIds,    // [BS,NG]
    const int*   __restrict__ grpIds,    // [BS,NP]
    float*       __restrict__ out)       // [BS,NQ,NG]
{
    __shared__ float wS[(NP + 1) * TQ];  // 32.9 KB: w tile -> prefix -> REUSED as predAct tile
    __shared__ float scanP[512];         // 2 KB: phase-B chunk totals
    __shared__ float redS[512];          // 2 KB: [0,256) P col-sums ; [256,512) ll col-sums
    __shared__ float lseS[NP];           // 1 KB: row LSEs (live across all tiles)
    __shared__ int   prS[NP];            // 1 KB: rank|m<<16 (live across all tiles)
    __shared__ float lseAct[TQ];
    __shared__ float szG[TQ], slG[TQ];
    __shared__ int   aidS[NG];
    __shared__ int   cntS[NG];           // atomic counters -> packed start|m<<16

    float* pTile = wS;                   // alive only after the prefix is consumed

    const int b   = blockIdx.x >> 1;
    const int qh  = (blockIdx.x & 1) * 256;   // q-half base
    const int t   = threadIdx.x;
    const int wv  = t >> 6, ln = t & 63;
    const int pr  = t >> 3;              // phase-A: 64 rows per iteration
    const int qo4 = (t & 7) * 4;

    // ---- LSE preamble: wave wv owns rows [wv*32, wv*32+32), 4 rows in flight ----
    {
        const float* base = att + (size_t)b * NP * NQ;
#pragma unroll
        for (int bt = 0; bt < 8; ++bt) {
            const int r0 = wv * 32 + bt * 4;
            float4 u0[4], u1[4];
#pragma unroll
            for (int i = 0; i < 4; ++i) {
                const float4* a4 = (const float4*)(base + (size_t)(r0 + i) * NQ);
                u0[i] = a4[2 * ln]; u1[i] = a4[2 * ln + 1];
            }
#pragma unroll
            for (int i = 0; i < 4; ++i) {
                float mx = fmaxf(fmaxf(fmaxf(u0[i].x, u0[i].y), fmaxf(u0[i].z, u0[i].w)),
                                 fmaxf(fmaxf(u1[i].x, u1[i].y), fmaxf(u1[i].z, u1[i].w)));
#pragma unroll
                for (int off = 1; off < 64; off <<= 1) mx = fmaxf(mx, __shfl_xor(mx, off, 64));
                float s = __expf(u0[i].x - mx) + __expf(u0[i].y - mx)
                        + __expf(u0[i].z - mx) + __expf(u0[i].w - mx)
                        + __expf(u1[i].x - mx) + __expf(u1[i].y - mx)
                        + __expf(u1[i].z - mx) + __expf(u1[i].w - mx);
#pragma unroll
                for (int off = 1; off < 64; off <<= 1) s += __shfl_xor(s, off, 64);
                if (ln == 0) lseS[r0 + i] = mx + __logf(s);
            }
        }
    }

    // ---- CSR build (once per block) ----
    if (t < NP) prS[t] = grpIds[b * NP + t];
    if (t < NG) { aidS[t] = actIds[b * NG + t]; cntS[t] = 0; }
    __syncthreads();

    int myPos = 0;
    if (t < NP) myPos = atomicAdd(&cntS[prS[t]], 1);
    __syncthreads();

    if (t < 64) {   // exclusive scan of group counts -> start | m<<16
        const int c0 = cntS[2 * t], c1 = cntS[2 * t + 1];
        const int ps = c0 + c1;
        int s = ps;
#pragma unroll
        for (int off = 1; off < 64; off <<= 1) {
            const int w = __shfl_up(s, off, 64);
            if (t >= off) s += w;
        }
        const int e = s - ps;
        cntS[2 * t]     = e | (c0 << 16);
        cntS[2 * t + 1] = (e + c0) | (c1 << 16);
    }
    __syncthreads();
    if (t < NP) {
        const int g  = prS[t];
        const int cs = cntS[g];
        prS[t] = ((cs & 0xffff) + myPos) | (cs & 0xffff0000);   // rank | m<<16
    }
    __syncthreads();

    // ---- 8 q-tiles ----
    for (int tt = 0; tt < 8; ++tt) {
        const int q0 = qh + tt * TQ;

        // att column tile (L3-warm from the preamble pass)
        float4 v[4];
#pragma unroll
        for (int it = 0; it < 4; ++it)
            v[it] = *(const float4*)(att + ((size_t)(b * NP + it * 64 + pr)) * NQ + q0 + qo4);

        // predAct rows for this tile (wave wv owns rows wv+8k)
        float pa0[4], pa1[4];
#pragma unroll
        for (int k = 0; k < 4; ++k) {
            const float* rowp = predAct + ((size_t)(b * NQ + q0 + wv + 8 * k)) * NC;
            pa0[k] = rowp[ln]; pa1[k] = rowp[ln + 64];
        }

        // phase A: fused w tile at permuted rank; accumulate per-q column sums
        float szL[4] = {0.f, 0.f, 0.f, 0.f}, slL[4] = {0.f, 0.f, 0.f, 0.f};
#pragma unroll
        for (int it = 0; it < 4; ++it) {
            const int p  = it * 64 + pr;
            const float l = lseS[p];
            const int pk = prS[p];
            const int rr = pk & 0xffff;
            const int m  = pk >> 16;
            const float im  = 1.f / (float)m;                       // m >= 1: p is a member
            const float inm = 1.f / fmaxf((float)(NP - m), 1.f);    // safe_nm like the reference
            float w[4];
            const float vv[4] = {v[it].x, v[it].y, v[it].z, v[it].w};
#pragma unroll
            for (int j = 0; j < 4; ++j) {
                const float x = vv[j] - l;                          // logP
                const float e = __expf(x);                          // P
                const float c = fminf(fmaxf(e, EPSC), 1.f - EPSC);
                const float ll = __logf(1.f - c);                   // log1p(-Pc)
                szL[j] += e;
                slL[j] += ll;
                w[j] = ll * inm - x * im;
            }
            *(float4*)(wS + rr * TQ + qo4) = *(float4*)w;
        }
#pragma unroll
        for (int j = 0; j < 4; ++j) {
#pragma unroll
            for (int off = 8; off < 64; off <<= 1) {
                szL[j] += __shfl_xor(szL[j], off, 64);
                slL[j] += __shfl_xor(slL[j], off, 64);
            }
        }
        if (ln < 8) {   // lane ln owns columns qo = 4*ln..4*ln+3
            *(float4*)(redS + wv * 32 + ln * 4)       = *(float4*)szL;
            *(float4*)(redS + 256 + wv * 32 + ln * 4) = *(float4*)slL;
        }

        // phase A2: activity row LSEs (one wave per row, 4 rows/wave)
#pragma unroll
        for (int k = 0; k < 4; ++k) {
            const int r = wv + 8 * k;
            float mx = fmaxf(pa0[k], pa1[k]);
#pragma unroll
            for (int off = 1; off < 64; off <<= 1) mx = fmaxf(mx, __shfl_xor(mx, off, 64));
            float s = __expf(pa0[k] - mx) + __expf(pa1[k] - mx);
#pragma unroll
            for (int off = 1; off < 64; off <<= 1) s += __shfl_xor(s, off, 64);
            if (ln == 0) lseAct[r] = mx + __logf(s);
        }
        __syncthreads();

        // cross-wave column-sum finish
        if (t < 64) {
            const int q = t & 31, which = t >> 5;
            const float* rb = redS + which * 256 + q;
            float s = 0.f;
#pragma unroll
            for (int w8 = 0; w8 < 8; ++w8) s += rb[w8 * 32];
            if (which == 0) szG[q] = s; else slG[q] = s;
        }

        // phase B: column-wise exclusive prefix over the 256 CSR rows (+ total)
        {
            const int cq = t & 31;          // column
            const int ck = t >> 5;          // chunk 0..15
            float pv[16];
            float run = 0.f;
#pragma unroll
            for (int i = 0; i < 16; ++i) {
                pv[i] = run;
                run += wS[(16 * ck + i) * TQ + cq];
            }
            scanP[ck * 32 + cq] = run;
            __syncthreads();
            float offs = 0.f;
#pragma unroll
            for (int j = 0; j < 15; ++j)
                if (j < ck) offs += scanP[j * 32 + cq];   // broadcast reads
#pragma unroll
            for (int i = 0; i < 16; ++i)
                wS[(16 * ck + i) * TQ + cq] = offs + pv[i];
            if (ck == 15) wS[NP * TQ + cq] = offs + run;  // grand total row
        }
        __syncthreads();

        // phase C1: grp + size cost into registers (prefix lookups)
        const int qoC = t & 31;
        const int g4A = (t >> 5) * 4;
        const int g4B = g4A + 64;
        float resA[4], resB[4];
        {
            const float sl = slG[qoC], pz = szG[qoC];
#pragma unroll
            for (int rep = 0; rep < 2; ++rep) {
                float* res = rep ? resB : resA;
                const int g4 = rep ? g4B : g4A;
#pragma unroll
                for (int j = 0; j < 4; ++j) {
                    const int g  = g4 + j;
                    const int cs = cntS[g];
                    const int m  = cs >> 16;
                    const int st = cs & 0xffff;
                    const float ms = wS[(st + m) * TQ + qoC] - wS[st * TQ + qoC];
                    const float mf  = (float)m;
                    const float nmf = fmaxf((float)(NP - m), 1.f);
                    float grp = ms - sl / nmf;     // = -mem/m - (sl-ml)/nm
                    float szc = fabsf(pz - mf) * (1.f / (float)NP);
                    if (m == 0) { grp = BIGC; szc = BIGC; }
                    res[j] = grp + szc;
                }
            }
        }
        __syncthreads();   // prefix reads done -> wS storage may be reused

        // phase C2: predAct tile into the wS region (stride 129, conflict-free)
#pragma unroll
        for (int k = 0; k < 4; ++k) {
            const int r = wv + 8 * k;
            pTile[r * PTS + ln]      = pa0[k];
            pTile[r * PTS + 64 + ln] = pa1[k];
        }
        __syncthreads();

        // phase C3: activity term + store
        {
            const float la = lseAct[qoC];
#pragma unroll
            for (int rep = 0; rep < 2; ++rep) {
                float* res = rep ? resB : resA;
                const int g4 = rep ? g4B : g4A;
#pragma unroll
                for (int j = 0; j < 4; ++j) {
                    const float av = pTile[qoC * PTS + aidS[g4 + j]];
                    res[j] += la - av;
                }
                *(float4*)(out + ((size_t)(b * NQ + q0 + qoC)) * NG + g4) = *(float4*)res;
            }
        }
        __syncthreads();   // wS/redS reused next tile
    }
}

extern "C" void kernel_launch(void* const* d_in, const int* in_sizes, int n_in,
                              void* d_out, int out_size, void* d_ws, size_t ws_size,
                              hipStream_t stream) {
    const float* predAct = (const float*)d_in[0];
    const float* att     = (const float*)d_in[1];
    const int*   actIds  = (const int*)d_in[2];
    const int*   grpIds  = (const int*)d_in[3];
    float*       out     = (float*)d_out;
    (void)d_ws; (void)ws_size;

    cost_fused<<<BS * 2, 512, 0, stream>>>(predAct, att, actIds, grpIds, out);
}